// Round 13
// baseline (738.661 us; speedup 1.0000x reference)
//
#include <hip/hip_runtime.h>
#include <hip/hip_bf16.h>
#include <math.h>

// Problem constants
#define NSUB   3
#define CFEAT  1024
#define KDIM   3072          // 3 * 32 * 32
#define MDIM   1568          // 32 * 49
#define BATCH  32
#define NKL    12            // k-steps of 64 per split (K=768); 4 splits

// Output layout (flat f32): ranking[32,3] | cam 3x2x[32,7,7] | feats 3x[32,1024,7,7]
#define OUT_CAM   96
#define OUT_FEAT  9504
#define FEAT_PER_BRANCH (BATCH * CFEAT * 49)   // 1605632

// Workspace byte offsets.
// A frags: 25*96*4 = 9600 chunks x 64 lanes x 16B
// W frags: 48*96*4 = 18432 chunks x 64 lanes x 16B
#define WS_A      0
#define WS_W      (9600 * 1024)
#define WS_POOLED (WS_W + 18432 * 1024)
#define WS_H      (WS_POOLED + NSUB * BATCH * CFEAT * 4)
#define WS_CAMP   (WS_H + NSUB * BATCH * 512 * 4)

typedef __attribute__((ext_vector_type(8))) short bf16x8;
typedef __attribute__((ext_vector_type(4))) float f32x4;

__device__ __forceinline__ short b16(float f){
    __hip_bfloat16 h = __float2bfloat16(f);
    return *reinterpret_cast<short*>(&h);
}
__device__ __forceinline__ bf16x8 pack8(float4 a, float4 b){
    bf16x8 r;
    r[0]=b16(a.x); r[1]=b16(a.y); r[2]=b16(a.z); r[3]=b16(a.w);
    r[4]=b16(b.x); r[5]=b16(b.y); r[6]=b16(b.z); r[7]=b16(b.w);
    return r;
}

// global -> LDS direct copy, 16B per lane (dest = wave-uniform base + lane*16)
typedef const __attribute__((address_space(1))) void* gas1_t;
typedef __attribute__((address_space(3))) void* las3_t;
__device__ __forceinline__ void gl_lds16(const short* g, char* l){
    __builtin_amdgcn_global_load_lds((gas1_t)g, (las3_t)l, 16, 0, 0);
}

// ---------------------------------------------------------------------------
// Prep: W frags (blocks 0..4607), A frags (4608..7007), feats bias-init
// (7008..11711; coalesced float4 — conv accumulates via atomicAdd on top).
// ---------------------------------------------------------------------------
__global__ __launch_bounds__(256) void prep_frag(
    const float* __restrict__ x, const float* __restrict__ w,
    const float* __restrict__ bbp,
    bf16x8* __restrict__ Af, bf16x8* __restrict__ Wf, float* __restrict__ out)
{
    int bid = blockIdx.x, t = threadIdx.x;
    if (bid < 4608) {
        int g = bid * 256 + t;
        int chunk = g >> 6, l = g & 63;
        int ni = chunk & 3, KT = (chunk >> 2) % 96, NTg = chunk / 384;
        int n = NTg * 64 + ni * 16 + (l & 15);       // 0..3071 = flat (i,c)
        int k = KT * 32 + (l >> 4) * 8;
        const float* src = w + (size_t)n * KDIM + k;
        Wf[(size_t)chunk * 64 + l] = pack8(*(const float4*)src, *(const float4*)(src + 4));
    } else if (bid < 7008) {
        int g = (bid - 4608) * 256 + t;
        int chunk = g >> 6, l = g & 63;
        int mi = chunk & 3, KT = (chunk >> 2) % 96, MT = chunk / 384;
        int m  = MT * 64 + mi * 16 + (l & 15);
        int k0 = KT * 32 + (l >> 4) * 8;
        bf16x8 v;
        if (m < MDIM) {
            int b = m / 49, p = m % 49, ph = p / 7, pw = p % 7;
            int ch = k0 >> 10, r = (k0 >> 5) & 31, s = k0 & 31;
            const float* src = x + (((size_t)(b*3 + ch)*224 + ph*32 + r)*224 + pw*32 + s);
            v = pack8(*(const float4*)src, *(const float4*)(src + 4));
        } else {
            v = (bf16x8){0,0,0,0,0,0,0,0};           // pad rows: zero
        }
        Af[(size_t)chunk * 64 + l] = v;
    } else {
        int g = (bid - 7008) * 256 + t;              // float4 index into feats
        int e = g * 4;
        float4 v;
#pragma unroll
        for (int j = 0; j < 4; ++j) {
            int ee = e + j;
            int i  = ee / FEAT_PER_BRANCH;
            int c  = ((ee % FEAT_PER_BRANCH) / 49) & 1023;
            ((float*)&v)[j] = bbp[i*CFEAT + c];
        }
        *(float4*)(out + OUT_FEAT + e) = v;
    }
}

// ---------------------------------------------------------------------------
// Conv GEMM bf16 MFMA, SPLIT-K=4. Body = round-12 (128x128 block, 4 waves,
// wave tile 64x64; A via gl_lds frag chunks dbuf 32KB; B global->reg).
// Each block does K=768 (12 k-steps); epilogue atomicAdd onto bias-init feats.
// Grid 1248 = 8 XCDs x (4 splits x 13 mt x 3 ntg):
//   xcd=d&7; s=d>>3; ks=s&3; s2=s>>2; mt=s2/3; ntg=xcd*3+s2%3.
// 4 blocks/CU co-resident (VGPR ~100, LDS 32KB) -> barrier chains of the four
// blocks interleave = the TLP that every 1-2 block/CU variant (R3-R12) lacked.
// ---------------------------------------------------------------------------
__global__ __launch_bounds__(256, 4) void conv_mfma(
    const bf16x8* __restrict__ Af, const bf16x8* __restrict__ Wf,
    float* __restrict__ out)
{
    __shared__ __align__(16) char lds[32768];   // 2 bufs x 16 chunks x 1KB

    const int d    = (int)blockIdx.x;           // 0..1247
    const int xcd  = d & 7;
    const int s    = d >> 3;                    // 0..155
    const int ks   = s & 3;                     // K split
    const int s2   = s >> 2;                    // 0..38
    const int mt   = s2 / 3;
    const int ntg  = xcd * 3 + (s2 % 3);        // 0..23 (128-col groups)
    const int i    = ntg >> 3;
    const int nt   = ntg & 7;

    const int t = threadIdx.x, wv = t >> 6, l = t & 63;
    const int wr = wv >> 1, wc = wv & 1;
    const int lrow = l & 15, lsl = l >> 4;
    const int kofs = ks * 6144;                 // 24 KT x 4 chunks x 64 lanes

    // ---- A staging: wave wv stages LDS slots wv*4+q; slot s2 = half*8+kk*4+mi
    const bf16x8* Ag[4]; int Ad[4];
#pragma unroll
    for (int q = 0; q < 4; ++q) {
        int sl   = wv*4 + q;
        int half = sl >> 3, kk = (sl >> 2) & 1, mi = sl & 3;
        Ag[q] = Af + (size_t)((2*mt + half)*384 + kk*4 + mi) * 64 + kofs + l;
        Ad[q] = sl * 1024;
    }

    // ---- B frag pointers: chunk = (i*16 + nt*2 + wc)*384 + (kt*2+kk)*4 + ni
    const int NTg = i*16 + nt*2 + wc;
    const bf16x8* Bp[4][2];
#pragma unroll
    for (int ni = 0; ni < 4; ++ni)
#pragma unroll
        for (int kk = 0; kk < 2; ++kk)
            Bp[ni][kk] = Wf + (size_t)(NTg*384 + kk*4 + ni) * 64 + kofs + l;

    f32x4 acc[4][4] = {};
    bf16x8 bgA[4][2], bgB[4][2];

    // prologue: stage kstep 0 -> buf0, B(0) -> bgA
#pragma unroll
    for (int q = 0; q < 4; ++q) gl_lds16((const short*)Ag[q], lds + Ad[q]);
#pragma unroll
    for (int ni = 0; ni < 4; ++ni)
#pragma unroll
        for (int kk = 0; kk < 2; ++kk)
            bgA[ni][kk] = *Bp[ni][kk];

    auto COMPUTE = [&](const char* base, bf16x8 (&BG)[4][2]) {
        bf16x8 af[4][2];
#pragma unroll
        for (int kk = 0; kk < 2; ++kk)
#pragma unroll
            for (int mi = 0; mi < 4; ++mi)
                af[mi][kk] = *(const bf16x8*)(base + (wr*8 + kk*4 + mi)*1024 + l*16);
        __builtin_amdgcn_s_setprio(1);
#pragma unroll
        for (int kk = 0; kk < 2; ++kk)
#pragma unroll
            for (int mi = 0; mi < 4; ++mi)
#pragma unroll
                for (int ni = 0; ni < 4; ++ni)
                    acc[mi][ni] = __builtin_amdgcn_mfma_f32_16x16x32_bf16(
                        af[mi][kk], BG[ni][kk], acc[mi][ni], 0, 0, 0);
        __builtin_amdgcn_s_setprio(0);
    };

    for (int kt = 0; kt < NKL; kt += 2) {
        // even: compute buf0/bgA; prefetch kt+1 -> buf1/bgB
        __syncthreads();
        if (kt + 1 < NKL) {
#pragma unroll
            for (int q = 0; q < 4; ++q)
                gl_lds16((const short*)(Ag[q] + (kt+1)*512), lds + 16384 + Ad[q]);
#pragma unroll
            for (int ni = 0; ni < 4; ++ni)
#pragma unroll
                for (int kk = 0; kk < 2; ++kk)
                    bgB[ni][kk] = Bp[ni][kk][(size_t)(kt+1)*512];
        }
        COMPUTE(lds, bgA);
        // odd: compute buf1/bgB; prefetch kt+2 -> buf0/bgA
        __syncthreads();
        if (kt + 2 < NKL) {
#pragma unroll
            for (int q = 0; q < 4; ++q)
                gl_lds16((const short*)(Ag[q] + (kt+2)*512), lds + Ad[q]);
#pragma unroll
            for (int ni = 0; ni < 4; ++ni)
#pragma unroll
                for (int kk = 0; kk < 2; ++kk)
                    bgA[ni][kk] = Bp[ni][kk][(size_t)(kt+2)*512];
        }
        COMPUTE(lds + 16384, bgB);
    }

    // epilogue: atomic accumulate into bias-initialized feats[i][b][c][p]
    float* featb = out + OUT_FEAT + (size_t)i * FEAT_PER_BRANCH;
#pragma unroll
    for (int mi = 0; mi < 4; ++mi) {
        int mbase = mt*128 + wr*64 + mi*16 + lsl*4;
#pragma unroll
        for (int r = 0; r < 4; ++r) {
            int m = mbase + r;
            if (m >= MDIM) continue;
            int b = m/49, p = m%49;
#pragma unroll
            for (int ni = 0; ni < 4; ++ni) {
                int n = nt*128 + wc*64 + ni*16 + lrow;
                atomicAdd(&featb[(size_t)(b*CFEAT + n)*49 + p], acc[mi][ni][r]);
            }
        }
    }
}

// ---------------------------------------------------------------------------
// Pool + partial CAM: 768 blocks (i, b, 128-channel chunk), 128 threads.
// ---------------------------------------------------------------------------
__global__ __launch_bounds__(128) void cam_pool(
    const float* __restrict__ feat, const float* __restrict__ cls_w,
    float* __restrict__ pooled, float* __restrict__ camp)
{
    __shared__ float fs[128][50];
    int bid = blockIdx.x;                  // (i*32+b)*8 + ch
    int i = bid >> 8, b = (bid >> 3) & 31, ch = bid & 7;
    int t = threadIdx.x;
    int c0 = ch * 128;
    const float* f = feat + ((size_t)(i*BATCH + b) * CFEAT + c0) * 49;

    for (int qq = 0; qq < 49; ++qq) {
        int e = qq*128 + t;
        fs[e / 49][e % 49] = f[e];
    }
    __syncthreads();

    {
        float s = 0.f;
#pragma unroll
        for (int k = 0; k < 49; ++k) s += fs[t][k];
        pooled[(size_t)(i*BATCH + b) * CFEAT + c0 + t] = s * (1.f/49.f);
    }

    if (t < 98) {
        int o = t / 49, p = t % 49;
        const float* w = cls_w + (size_t)i * 2 * CFEAT + o * CFEAT + c0;
        float s = 0.f;
        for (int c = 0; c < 128; ++c) s += w[c] * fs[c][p];
        camp[(size_t)bid * 98 + t] = s;
    }
}

// ---------------------------------------------------------------------------
// MLP layer 1 (blocks 0..47) + CAM finalize (blocks 48..84).
// ---------------------------------------------------------------------------
__global__ __launch_bounds__(256) void mlp1_kernel(
    const float* __restrict__ pooled, const float* __restrict__ p1w,
    const float* __restrict__ p1b, float* __restrict__ h,
    const float* __restrict__ camp, float* __restrict__ out_cam)
{
    if (blockIdx.x >= 48) {                 // CAM finalize: sum 8 chunk partials
        int fid = (blockIdx.x - 48) * 256 + threadIdx.x;
        if (fid < NSUB * 2 * MDIM) {
            int io = fid / MDIM, rem = fid % MDIM;
            int b = rem / 49, p = rem % 49;
            int i = io >> 1, o = io & 1;
            float s = 0.f;
#pragma unroll
            for (int c = 0; c < 8; ++c)
                s += camp[(size_t)(((i*BATCH + b)*8) + c) * 98 + o*49 + p];
            out_cam[fid] = fmaxf(s, 0.f);
        }
        return;
    }
    __shared__ float ps[32 * 256];
    int i = blockIdx.x >> 4, jc = blockIdx.x & 15;
    int t = threadIdx.x;
    int j = jc*32 + (t & 31);
    int bg = (t >> 5) * 4;
    float acc[4] = {};
    const float* wrow = p1w + ((size_t)i*512 + j) * CFEAT;
    for (int kc = 0; kc < 4; ++kc) {
        __syncthreads();
#pragma unroll
        for (int qq = 0; qq < 8; ++qq) {
            int f4 = t + qq*256;                 // 0..2047 float4s
            int b = f4 >> 6, k4 = (f4 & 63) * 4;
            *(float4*)&ps[b*256 + k4] =
                *(const float4*)&pooled[((size_t)i*32 + b)*CFEAT + kc*256 + k4];
        }
        __syncthreads();
        const float* wk = wrow + kc*256;
        for (int k = 0; k < 256; k += 4) {
            float4 w4 = *(const float4*)(wk + k);
#pragma unroll
            for (int qq = 0; qq < 4; ++qq) {
                const float* pr = &ps[(bg + qq)*256 + k];  // wave-uniform: broadcast
                acc[qq] += w4.x*pr[0] + w4.y*pr[1] + w4.z*pr[2] + w4.w*pr[3];
            }
        }
    }
    float bias = p1b[i*512 + j];
#pragma unroll
    for (int qq = 0; qq < 4; ++qq)
        h[((size_t)i*32 + bg + qq)*512 + j] = fmaxf(acc[qq] + bias, 0.f);
}

// ---------------------------------------------------------------------------
// MLP layer 2 + softmax[:,1]: block per branch.
// ---------------------------------------------------------------------------
__global__ void mlp2_kernel(const float* __restrict__ h, const float* __restrict__ p2w,
                            const float* __restrict__ p2b, float* __restrict__ out)
{
    __shared__ float part[256];
    int i = blockIdx.x, t = threadIdx.x;
    int b = t & 31, kc = t >> 5;                 // kc 0..7, 64 k each
    const float* hv = h + ((size_t)i*32 + b)*512 + kc*64;
    const float* w0 = p2w + (size_t)i*1024 + kc*64;
    const float* w1 = w0 + 512;
    float s = 0.f;
    for (int k = 0; k < 64; ++k) s += hv[k] * (w1[k] - w0[k]);
    part[t] = s;
    __syncthreads();
    if (t < 32) {
        float d = 0.f;
#pragma unroll
        for (int qq = 0; qq < 8; ++qq) d += part[qq*32 + t];
        d += p2b[i*2 + 1] - p2b[i*2 + 0];
        out[b*NSUB + i] = 1.f / (1.f + expf(-d));
    }
}

// ---------------------------------------------------------------------------
extern "C" void kernel_launch(void* const* d_in, const int* in_sizes, int n_in,
                              void* d_out, int out_size, void* d_ws, size_t ws_size,
                              hipStream_t stream)
{
    const float* x    = (const float*)d_in[0];
    const float* Wb   = (const float*)d_in[1];
    const float* bbp  = (const float*)d_in[2];
    const float* p1w  = (const float*)d_in[3];
    const float* p1b  = (const float*)d_in[4];
    const float* p2w  = (const float*)d_in[5];
    const float* p2b  = (const float*)d_in[6];
    const float* clsw = (const float*)d_in[7];
    float* out = (float*)d_out;

    char* ws = (char*)d_ws;
    bf16x8* Af    = (bf16x8*)(ws + WS_A);
    bf16x8* Wf    = (bf16x8*)(ws + WS_W);
    float* pooled = (float*)(ws + WS_POOLED);
    float* hbuf   = (float*)(ws + WS_H);
    float* camp   = (float*)(ws + WS_CAMP);

    // prep: W frags + A frags + feats bias-init (4.8M floats / 1024 per block)
    prep_frag<<<4608 + 2400 + 4704, 256, 0, stream>>>(x, Wb, bbp, Af, Wf, out);
    conv_mfma<<<1248, 256, 0, stream>>>(Af, Wf, out);
    cam_pool<<<NSUB*BATCH*8, 128, 0, stream>>>(out + OUT_FEAT, clsw, pooled, camp);
    mlp1_kernel<<<48 + 37, 256, 0, stream>>>(pooled, p1w, p1b, hbuf, camp, out + OUT_CAM);
    mlp2_kernel<<<NSUB, 256, 0, stream>>>(hbuf, p2w, p2b, out);
}

// Round 14
// 110.421 us; speedup vs baseline: 6.6895x; 6.6895x over previous
//
#include <hip/hip_runtime.h>
#include <hip/hip_bf16.h>
#include <math.h>

// Problem constants
#define NSUB   3
#define CFEAT  1024
#define KDIM   3072          // 3 * 32 * 32
#define MDIM   1568          // 32 * 49
#define BATCH  32
#define NKT    96            // K tiles of 32

// Output layout (flat f32): ranking[32,3] | cam 3x2x[32,7,7] | feats 3x[32,1024,7,7]
#define OUT_CAM   96
#define OUT_FEAT  9504
#define FEAT_PER_BRANCH (BATCH * CFEAT * 49)   // 1605632

// Workspace byte offsets.
#define WS_A      0
#define WS_W      (9600 * 1024)
#define WS_POOLED (WS_W + 18432 * 1024)
#define WS_H      (WS_POOLED + NSUB * BATCH * CFEAT * 4)
#define WS_CAMP   (WS_H + NSUB * BATCH * 512 * 4)

typedef __attribute__((ext_vector_type(8))) short bf16x8;
typedef __attribute__((ext_vector_type(4))) float f32x4;

__device__ __forceinline__ short b16(float f){
    __hip_bfloat16 h = __float2bfloat16(f);
    return *reinterpret_cast<short*>(&h);
}
__device__ __forceinline__ bf16x8 pack8(float4 a, float4 b){
    bf16x8 r;
    r[0]=b16(a.x); r[1]=b16(a.y); r[2]=b16(a.z); r[3]=b16(a.w);
    r[4]=b16(b.x); r[5]=b16(b.y); r[6]=b16(b.z); r[7]=b16(b.w);
    return r;
}

// Volatile inline-asm 16B global load: CANNOT be folded/reordered by the
// compiler (round-8/9 lesson: ordinary loads sink across sched_barrier at IR
// level, collapsing any source-level register pipeline; VGPR=104 proved it).
__device__ __forceinline__ bf16x8 gld16(const bf16x8* p){
    bf16x8 r;
    asm volatile("global_load_dwordx4 %0, %1, off"
                 : "=v"(r) : "v"(p) : "memory");
    return r;
}

// ---------------------------------------------------------------------------
// Prep into MFMA-fragment layout (unchanged; validated rounds 7-12).
// Fragment (16x16x32 bf16 A/B operand): lane l holds row (l&15), k=(l>>4)*8+j.
// Chunk index: A: (MT64*96 + KT)*4 + mi ; W: (NTg*96 + KT)*4 + ni.
// ---------------------------------------------------------------------------
__global__ __launch_bounds__(256) void prep_frag(
    const float* __restrict__ x, const float* __restrict__ w,
    bf16x8* __restrict__ Af, bf16x8* __restrict__ Wf)
{
    int bid = blockIdx.x, t = threadIdx.x;
    if (bid < 4608) {
        int g = bid * 256 + t;
        int chunk = g >> 6, l = g & 63;
        int ni = chunk & 3, KT = (chunk >> 2) % 96, NTg = chunk / 384;
        int n = NTg * 64 + ni * 16 + (l & 15);       // 0..3071 = flat (i,c)
        int k = KT * 32 + (l >> 4) * 8;
        const float* src = w + (size_t)n * KDIM + k;
        Wf[(size_t)chunk * 64 + l] = pack8(*(const float4*)src, *(const float4*)(src + 4));
    } else {
        int g = (bid - 4608) * 256 + t;
        int chunk = g >> 6, l = g & 63;
        int mi = chunk & 3, KT = (chunk >> 2) % 96, MT = chunk / 384;
        int m  = MT * 64 + mi * 16 + (l & 15);
        int k0 = KT * 32 + (l >> 4) * 8;
        bf16x8 v;
        if (m < MDIM) {
            int b = m / 49, p = m % 49, ph = p / 7, pw = p % 7;
            int ch = k0 >> 10, r = (k0 >> 5) & 31, s = k0 & 31;
            const float* src = x + (((size_t)(b*3 + ch)*224 + ph*32 + r)*224 + pw*32 + s);
            v = pack8(*(const float4*)src, *(const float4*)(src + 4));
        } else {
            v = (bf16x8){0,0,0,0,0,0,0,0};           // pad rows: zero
        }
        Af[(size_t)chunk * 64 + l] = v;
    }
}

// ---------------------------------------------------------------------------
// Conv GEMM bf16 MFMA — round-9 structure (no staging LDS, no barriers,
// wave tile 64x64, 600 blocks x 2 waves sharing the A tile via L1) with a
// REAL depth-4 register pipeline: volatile-asm loads + counted vmcnt waits.
// Per KT group: 8 loads (4 A + 4 B). Steady state: 4 groups issued ahead,
// wait vmcnt(24) retires the oldest (3 x 8 = 24 left in flight ~ 240+ cy
// cover). Tail peeled with vmcnt 24/16/8/0. sched_barrier(0) after each wait
// (rule 18: MFMA hoists past asm waitcnt otherwise).
// Epilogue via per-wave LDS tile (pad 65) -> coalesced writes (R8 win).
// ---------------------------------------------------------------------------
__global__ __launch_bounds__(128, 2) void conv_mfma(
    const bf16x8* __restrict__ Af, const bf16x8* __restrict__ Wf,
    const float* __restrict__ bb, float* __restrict__ out)
{
    __shared__ float eplds[2][64 * 65];         // epilogue only

    int bid = (int)blockIdx.x;
    bid = (bid & 7) * 75 + (bid >> 3);          // bijective XCD swizzle (600=8*75)
    const int i   = bid / 200;
    const int rem = bid % 200;
    const int NTb = rem / 25, MT = rem % 25;

    const int wv = threadIdx.x >> 6, l = threadIdx.x & 63;
    const int NT = NTb + wv * 8;
    const int lrow = l & 15, q = l >> 4;

    const bf16x8* Ab = Af + (size_t)(MT * 384) * 64 + l;          // + KT*256 + mi*64
    const bf16x8* Bb = Wf + (size_t)((i*16 + NT) * 384) * 64 + l; // + KT*256 + ni*64

    f32x4 acc[4][4] = {};
    bf16x8 a0[4], b0[4], a1[4], b1[4], a2[4], b2[4], a3[4], b3[4];

#define ISSUE(Ax, Bx, KT) {                                        \
    const bf16x8* pA_ = Ab + (KT) * 256;                           \
    const bf16x8* pB_ = Bb + (KT) * 256;                           \
    Ax[0] = gld16(pA_);       Ax[1] = gld16(pA_ + 64);             \
    Ax[2] = gld16(pA_ + 128); Ax[3] = gld16(pA_ + 192);            \
    Bx[0] = gld16(pB_);       Bx[1] = gld16(pB_ + 64);             \
    Bx[2] = gld16(pB_ + 128); Bx[3] = gld16(pB_ + 192); }

#define MFMAT(Ax, Bx) {                                            \
    __builtin_amdgcn_s_setprio(1);                                 \
    _Pragma("unroll") for (int mi = 0; mi < 4; ++mi)               \
    _Pragma("unroll") for (int ni = 0; ni < 4; ++ni)               \
        acc[mi][ni] = __builtin_amdgcn_mfma_f32_16x16x32_bf16(     \
            Ax[mi], Bx[ni], acc[mi][ni], 0, 0, 0);                 \
    __builtin_amdgcn_s_setprio(0); }

#define WAITV(N) { asm volatile("s_waitcnt vmcnt(" #N ")" ::: "memory"); \
                   __builtin_amdgcn_sched_barrier(0); }

    // prologue: 4 groups in flight (32 loads)
    ISSUE(a0, b0, 0); ISSUE(a1, b1, 1); ISSUE(a2, b2, 2); ISSUE(a3, b3, 3);

    // steady loop: consume group kt+j (buffer j), issue kt+4+j. kt<=88 ->
    // last issue = 95; no branches in body.
    for (int kt = 0; kt <= 88; kt += 4) {
        WAITV(24); MFMAT(a0, b0); ISSUE(a0, b0, kt + 4);
        WAITV(24); MFMAT(a1, b1); ISSUE(a1, b1, kt + 5);
        WAITV(24); MFMAT(a2, b2); ISSUE(a2, b2, kt + 6);
        WAITV(24); MFMAT(a3, b3); ISSUE(a3, b3, kt + 7);
    }
    // tail: groups 92..95 already in buffers 0..3
    WAITV(24); MFMAT(a0, b0);
    WAITV(16); MFMAT(a1, b1);
    WAITV(8);  MFMAT(a2, b2);
    WAITV(0);  MFMAT(a3, b3);

#undef ISSUE
#undef MFMAT
#undef WAITV

    // ---- epilogue: acc -> per-wave LDS tile -> coalesced global writes ----
    float bias[4];
#pragma unroll
    for (int ni = 0; ni < 4; ++ni)
        bias[ni] = bb[i*CFEAT + NT*64 + ni*16 + lrow];
    float* ep = eplds[wv];
#pragma unroll
    for (int mi = 0; mi < 4; ++mi)
#pragma unroll
        for (int ni = 0; ni < 4; ++ni)
#pragma unroll
            for (int rr = 0; rr < 4; ++rr)
                ep[(mi*16 + q*4 + rr) * 65 + ni*16 + lrow] = acc[mi][ni][rr] + bias[ni];

    // same-wave LDS readback: compiler orders via lgkmcnt
    float* featb = out + OUT_FEAT + (size_t)i * FEAT_PER_BRANCH;
    int m = MT*64 + l;
    if (m < MDIM) {
        int b = m / 49, p = m % 49;
        float* base = featb + (size_t)(b*CFEAT + NT*64) * 49 + p;
#pragma unroll 8
        for (int c = 0; c < 64; ++c)
            base[c * 49] = ep[l*65 + c];
    }
}

// ---------------------------------------------------------------------------
// Pool + partial CAM: 768 blocks (i, b, 128-channel chunk), 128 threads.
// ---------------------------------------------------------------------------
__global__ __launch_bounds__(128) void cam_pool(
    const float* __restrict__ feat, const float* __restrict__ cls_w,
    float* __restrict__ pooled, float* __restrict__ camp)
{
    __shared__ float fs[128][50];
    int bid = blockIdx.x;                  // (i*32+b)*8 + ch
    int i = bid >> 8, b = (bid >> 3) & 31, ch = bid & 7;
    int t = threadIdx.x;
    int c0 = ch * 128;
    const float* f = feat + ((size_t)(i*BATCH + b) * CFEAT + c0) * 49;

    for (int qq = 0; qq < 49; ++qq) {
        int e = qq*128 + t;
        fs[e / 49][e % 49] = f[e];
    }
    __syncthreads();

    {
        float s = 0.f;
#pragma unroll
        for (int k = 0; k < 49; ++k) s += fs[t][k];
        pooled[(size_t)(i*BATCH + b) * CFEAT + c0 + t] = s * (1.f/49.f);
    }

    if (t < 98) {
        int o = t / 49, p = t % 49;
        const float* w = cls_w + (size_t)i * 2 * CFEAT + o * CFEAT + c0;
        float s = 0.f;
        for (int c = 0; c < 128; ++c) s += w[c] * fs[c][p];
        camp[(size_t)bid * 98 + t] = s;
    }
}

// ---------------------------------------------------------------------------
// MLP layer 1 (blocks 0..47) + CAM finalize (blocks 48..84).
// ---------------------------------------------------------------------------
__global__ __launch_bounds__(256) void mlp1_kernel(
    const float* __restrict__ pooled, const float* __restrict__ p1w,
    const float* __restrict__ p1b, float* __restrict__ h,
    const float* __restrict__ camp, float* __restrict__ out_cam)
{
    if (blockIdx.x >= 48) {                 // CAM finalize: sum 8 chunk partials
        int fid = (blockIdx.x - 48) * 256 + threadIdx.x;
        if (fid < NSUB * 2 * MDIM) {
            int io = fid / MDIM, rem = fid % MDIM;
            int b = rem / 49, p = rem % 49;
            int i = io >> 1, o = io & 1;
            float s = 0.f;
#pragma unroll
            for (int c = 0; c < 8; ++c)
                s += camp[(size_t)(((i*BATCH + b)*8) + c) * 98 + o*49 + p];
            out_cam[fid] = fmaxf(s, 0.f);
        }
        return;
    }
    __shared__ float ps[32 * 256];
    int i = blockIdx.x >> 4, jc = blockIdx.x & 15;
    int t = threadIdx.x;
    int j = jc*32 + (t & 31);
    int bg = (t >> 5) * 4;
    float acc[4] = {};
    const float* wrow = p1w + ((size_t)i*512 + j) * CFEAT;
    for (int kc = 0; kc < 4; ++kc) {
        __syncthreads();
#pragma unroll
        for (int qq = 0; qq < 8; ++qq) {
            int f4 = t + qq*256;                 // 0..2047 float4s
            int b = f4 >> 6, k4 = (f4 & 63) * 4;
            *(float4*)&ps[b*256 + k4] =
                *(const float4*)&pooled[((size_t)i*32 + b)*CFEAT + kc*256 + k4];
        }
        __syncthreads();
        const float* wk = wrow + kc*256;
        for (int k = 0; k < 256; k += 4) {
            float4 w4 = *(const float4*)(wk + k);
#pragma unroll
            for (int qq = 0; qq < 4; ++qq) {
                const float* pr = &ps[(bg + qq)*256 + k];  // wave-uniform: broadcast
                acc[qq] += w4.x*pr[0] + w4.y*pr[1] + w4.z*pr[2] + w4.w*pr[3];
            }
        }
    }
    float bias = p1b[i*512 + j];
#pragma unroll
    for (int qq = 0; qq < 4; ++qq)
        h[((size_t)i*32 + bg + qq)*512 + j] = fmaxf(acc[qq] + bias, 0.f);
}

// ---------------------------------------------------------------------------
// MLP layer 2 + softmax[:,1]: block per branch.
// ---------------------------------------------------------------------------
__global__ void mlp2_kernel(const float* __restrict__ h, const float* __restrict__ p2w,
                            const float* __restrict__ p2b, float* __restrict__ out)
{
    __shared__ float part[256];
    int i = blockIdx.x, t = threadIdx.x;
    int b = t & 31, kc = t >> 5;                 // kc 0..7, 64 k each
    const float* hv = h + ((size_t)i*32 + b)*512 + kc*64;
    const float* w0 = p2w + (size_t)i*1024 + kc*64;
    const float* w1 = w0 + 512;
    float s = 0.f;
    for (int k = 0; k < 64; ++k) s += hv[k] * (w1[k] - w0[k]);
    part[t] = s;
    __syncthreads();
    if (t < 32) {
        float d = 0.f;
#pragma unroll
        for (int qq = 0; qq < 8; ++qq) d += part[qq*32 + t];
        d += p2b[i*2 + 1] - p2b[i*2 + 0];
        out[b*NSUB + i] = 1.f / (1.f + expf(-d));
    }
}

// ---------------------------------------------------------------------------
extern "C" void kernel_launch(void* const* d_in, const int* in_sizes, int n_in,
                              void* d_out, int out_size, void* d_ws, size_t ws_size,
                              hipStream_t stream)
{
    const float* x    = (const float*)d_in[0];
    const float* Wb   = (const float*)d_in[1];
    const float* bbp  = (const float*)d_in[2];
    const float* p1w  = (const float*)d_in[3];
    const float* p1b  = (const float*)d_in[4];
    const float* p2w  = (const float*)d_in[5];
    const float* p2b  = (const float*)d_in[6];
    const float* clsw = (const float*)d_in[7];
    float* out = (float*)d_out;

    char* ws = (char*)d_ws;
    bf16x8* Af    = (bf16x8*)(ws + WS_A);
    bf16x8* Wf    = (bf16x8*)(ws + WS_W);
    float* pooled = (float*)(ws + WS_POOLED);
    float* hbuf   = (float*)(ws + WS_H);
    float* camp   = (float*)(ws + WS_CAMP);

    prep_frag<<<4608 + 2400, 256, 0, stream>>>(x, Wb, Af, Wf);
    conv_mfma<<<600, 128, 0, stream>>>(Af, Wf, bbp, out);
    cam_pool<<<NSUB*BATCH*8, 128, 0, stream>>>(out + OUT_FEAT, clsw, pooled, camp);
    mlp1_kernel<<<48 + 37, 256, 0, stream>>>(pooled, p1w, p1b, hbuf, camp, out + OUT_CAM);
    mlp2_kernel<<<NSUB, 256, 0, stream>>>(hbuf, p2w, p2b, out);
}